// Round 1
// baseline (528.023 us; speedup 1.0000x reference)
//
#include <hip/hip_runtime.h>
#include <float.h>

#define NEG_SLOPE 0.2f

__device__ __forceinline__ float lrelu(float x) { return x >= 0.0f ? x : NEG_SLOPE * x; }

// ============ conv: 1 px/thread, weights via wave-uniform scalar (SGPR) loads ============
// Work decomposition: one thread per OUTPUT pixel -> ~3200 waves (~12.5 waves/CU) so
// memory latency is hidden by TLP (previous 4px/thread version had 812 waves = 1/SIMD,
// OccupancyPercent 5%, VALUBusy 13%).
// Weights: original (co, c, ky, kx) layout is contiguous over the 16 (ky,kx) taps for a
// fixed (co,c). Loop c -> co -> taps, so every weight read is a uniform contiguous
// 16-float chunk -> s_load_dwordx* into SGPRs, FMA is v_fmac_f32 v,s,v. No LDS at all.
struct ConvSeg {
    const float* in; const float* wa; const float* wb; const float* ba; const float* bb;
    float* out;
    int CIN, H, W, right, nit, npix, blk0;
};
struct ConvTab { ConvSeg seg[10]; };

__device__ __forceinline__ void accum16(float m[16], const float wv[16],
                                        const float* __restrict__ wa, int CIN, int c) {
#pragma unroll
    for (int co = 0; co < 16; co++) {
        const float* __restrict__ wc = wa + (size_t)(co * CIN + c) * 16;
#pragma unroll
        for (int kk = 0; kk < 16; kk++) m[co] = fmaf(wv[kk], wc[kk], m[co]);
    }
}

__global__ __launch_bounds__(256)
void conv_uber(ConvTab tab) {
    int si = 0;
#pragma unroll
    for (int i = 1; i < 10; i++) if ((int)blockIdx.x >= tab.seg[i].blk0) si = i;
    const ConvSeg sg = tab.seg[si];
    const int CIN = sg.CIN, W = sg.W, H = sg.H;

    const int t = ((int)blockIdx.x - sg.blk0) * 256 + (int)threadIdx.x;
    if (t >= sg.nit) return;   // no barriers in this kernel -> early exit is safe

    const float* __restrict__ wa = sg.wa;
    float m[16];
#pragma unroll
    for (int co = 0; co < 16; co++) m[co] = 0.f;

    if (sg.right) {
        // stride (4,1): out px (y,x) reads rows 4y..4y+3, cols x..x+3 (zero-pad past W-1)
        const int y = t / W, x = t - y * W;
        const float* ib = sg.in + (size_t)(4 * y) * W + x;
        if (x + 4 <= W) {   // fast path: ~19/20 waves are fully interior
            for (int c = 0; c < CIN; c++) {
                const float* rb = ib + (size_t)c * H * W;
                float wv[16];
#pragma unroll
                for (int r = 0; r < 4; r++)
#pragma unroll
                    for (int k = 0; k < 4; k++) wv[r * 4 + k] = rb[r * W + k];  // lanes coalesced
                accum16(m, wv, wa, CIN, c);
            }
        } else {            // right-edge pad: predicated loads, 3 columns per row only
            for (int c = 0; c < CIN; c++) {
                const float* rb = ib + (size_t)c * H * W;
                float wv[16];
#pragma unroll
                for (int r = 0; r < 4; r++)
#pragma unroll
                    for (int k = 0; k < 4; k++) wv[r * 4 + k] = (x + k < W) ? rb[r * W + k] : 0.f;
                accum16(m, wv, wa, CIN, c);
            }
        }
    } else {
        // stride (4,4): out px (y,x) reads rows 4y..4y+3, cols 4x..4x+3 (aligned float4)
        const int W4 = W >> 2;
        const int y = t / W4, x = t - y * W4;
        const float* ib = sg.in + (size_t)(4 * y) * W + 4 * x;
        for (int c = 0; c < CIN; c++) {
            const float* rb = ib + (size_t)c * H * W;
            float wv[16];
#pragma unroll
            for (int r = 0; r < 4; r++) {
                float4 f = *(const float4*)(rb + r * W);
                wv[r * 4 + 0] = f.x; wv[r * 4 + 1] = f.y;
                wv[r * 4 + 2] = f.z; wv[r * 4 + 3] = f.w;
            }
            accum16(m, wv, wa, CIN, c);
        }
    }

    // epilogue: bias + lrelu, 1x1 conv (uniform scalar weights), coalesced stores
    const float* __restrict__ ba = sg.ba;
    const float* __restrict__ wb = sg.wb;
    const float* __restrict__ bb = sg.bb;
#pragma unroll
    for (int co = 0; co < 16; co++) m[co] = lrelu(m[co] + ba[co]);
    float o[16];
#pragma unroll
    for (int co = 0; co < 16; co++) {
        const float* __restrict__ wr = wb + co * 16;   // contiguous over k -> s_load
        float a = 0.f;
#pragma unroll
        for (int k = 0; k < 16; k++) a = fmaf(m[k], wr[k], a);
        o[co] = lrelu(a + bb[co]);
    }
#pragma unroll
    for (int co = 0; co < 16; co++)
        sg.out[(size_t)co * sg.npix + t] = o[co];
}

// ============ über cost-volume + argmin + hyp: 16 px x 16 d-chunks per block ============
struct CvSeg {
    const float* tl; const float* tr; const float* feat;
    const float* dw; const float* db;
    float* cv; float* hyp;
    int h, w4, w, D, gpc, CF, blk0;
};
struct CvTab { CvSeg seg[5]; };

__global__ __launch_bounds__(256)
void cv_hyp_uber(CvTab tab) {
    __shared__ float smin[256];
    __shared__ int sarg[256];

    int si = 0;
#pragma unroll
    for (int i = 1; i < 5; i++) if ((int)blockIdx.x >= tab.seg[i].blk0) si = i;
    const CvSeg sg = tab.seg[si];

    const int npix = sg.h * sg.w4;
    const int p = threadIdx.x & 15, chunk = threadIdx.x >> 4;
    const int pix = ((int)blockIdx.x - sg.blk0) * 16 + p;
    const bool valid = pix < npix;

    float mloc = FLT_MAX; int aloc = 0;
    if (valid) {
        int y = pix / sg.w4, j = pix - y * sg.w4;
        float tlv[16]; float sumabs = 0.f;
#pragma unroll
        for (int c = 0; c < 16; c++) { tlv[c] = sg.tl[(size_t)c * npix + pix]; sumabs += fabsf(tlv[c]); }

        int ngroups = sg.D >> 2;
        int g0 = chunk * sg.gpc;
        int g1 = min(ngroups, g0 + sg.gpc);
        const float* trrow = sg.tr + (size_t)y * sg.w;
        int hw = sg.h * sg.w;

        float carry[16];
        int b0 = 4 * j - 4 * g0;
        if (g0 < g1 && b0 >= 0) {
#pragma unroll
            for (int c = 0; c < 16; c++) carry[c] = trrow[(size_t)c * hw + b0];
        }
        for (int g = g0; g < g1; g++) {
            int b = 4 * j - 4 * g;
            float a0, a1, a2, a3;
            if (b >= 4) {
                a0 = a1 = a2 = a3 = 0.f;
#pragma unroll
                for (int c = 0; c < 16; c++) {
                    float4 f0 = *(const float4*)(trrow + (size_t)c * hw + (b - 4));
                    float tv = tlv[c];
                    a0 += fabsf(tv - carry[c]);
                    a1 += fabsf(tv - f0.w);
                    a2 += fabsf(tv - f0.z);
                    a3 += fabsf(tv - f0.y);
                    carry[c] = f0.x;
                }
            } else if (b == 0) {
                a0 = 0.f; a1 = a2 = a3 = sumabs;
#pragma unroll
                for (int c = 0; c < 16; c++) a0 += fabsf(tlv[c] - carry[c]);
            } else {
                a0 = a1 = a2 = a3 = sumabs;
            }
            float* cvp = sg.cv + (size_t)(4 * g) * npix + pix;
            cvp[0] = a0; cvp[npix] = a1; cvp[2 * (size_t)npix] = a2; cvp[3 * (size_t)npix] = a3;
            if (a0 < mloc) { mloc = a0; aloc = 4 * g; }
            if (a1 < mloc) { mloc = a1; aloc = 4 * g + 1; }
            if (a2 < mloc) { mloc = a2; aloc = 4 * g + 2; }
            if (a3 < mloc) { mloc = a3; aloc = 4 * g + 3; }
        }
    }
    smin[threadIdx.x] = mloc;
    sarg[threadIdx.x] = aloc;
    __syncthreads();

    if (threadIdx.x < 16 && valid) {
        float mn = smin[threadIdx.x]; int arg = sarg[threadIdx.x];
#pragma unroll
        for (int c2 = 1; c2 < 16; c2++) {    // ascending chunk = ascending d; strict <
            float v = smin[c2 * 16 + threadIdx.x];
            if (v < mn) { mn = v; arg = sarg[c2 * 16 + threadIdx.x]; }
        }
        float acc[13];
#pragma unroll
        for (int o = 0; o < 13; o++) acc[o] = sg.dw[o * (sg.CF + 1)] * mn;
        for (int c = 0; c < sg.CF; c++) {
            float v = sg.feat[(size_t)c * npix + pix];
#pragma unroll
            for (int o = 0; o < 13; o++) acc[o] = fmaf(v, sg.dw[o * (sg.CF + 1) + 1 + c], acc[o]);
        }
        sg.hyp[pix] = (float)arg;
        sg.hyp[npix + pix] = 0.f;
        sg.hyp[2 * (size_t)npix + pix] = 0.f;
#pragma unroll
        for (int o = 0; o < 13; o++) sg.hyp[(size_t)(3 + o) * npix + pix] = lrelu(acc[o] + sg.db[o]);
    }
}

extern "C" void kernel_launch(void* const* d_in, const int* in_sizes, int n_in,
                              void* d_out, int out_size, void* d_ws, size_t ws_size,
                              hipStream_t stream) {
    (void)in_sizes; (void)n_in; (void)out_size; (void)ws_size;
    float* out = (float*)d_out;
    float* ws = (float*)d_ws;

    const int C[5] = {32, 24, 24, 16, 16};
    const int H[5] = {24, 48, 96, 192, 384};
    const int W[5] = {80, 160, 320, 640, 1280};
    const int D[5] = {20, 40, 80, 160, 320};
    const int wa_i[5] = {10, 14, 18, 22, 26};
    const int dw_i[5] = {30, 32, 34, 36, 38};

    const size_t cv_off[5]  = {0, 2400, 21600, 175200, 1404000};
    const size_t hyp_off[5] = {11234400, 11236320, 11244000, 11274720, 11397600};
    const size_t tl_off[5] = {0, 9600, 48000, 201600, 816000};
    const size_t tr_off[5] = {1920, 17280, 78720, 324480, 1307520};

    const float* fl[5] = {(const float*)d_in[0], (const float*)d_in[1], (const float*)d_in[2],
                          (const float*)d_in[3], (const float*)d_in[4]};
    const float* fr[5] = {(const float*)d_in[5], (const float*)d_in[6], (const float*)d_in[7],
                          (const float*)d_in[8], (const float*)d_in[9]};

    // ---- conv table: biggest segments first; 1 output px per thread ----
    const int ord_lvl[10]  = {4, 4, 3, 3, 2, 2, 1, 1, 0, 0};
    const int ord_side[10] = {1, 0, 1, 0, 1, 0, 1, 0, 1, 0};   // 1 = right
    ConvTab ct;
    int blk = 0;
    for (int i = 0; i < 10; i++) {
        int l = ord_lvl[i]; bool right = ord_side[i];
        ConvSeg& s = ct.seg[i];
        s.in = right ? fr[l] : fl[l];
        s.wa = (const float*)d_in[wa_i[l]];
        s.ba = (const float*)d_in[wa_i[l] + 1];
        s.wb = (const float*)d_in[wa_i[l] + 2];
        s.bb = (const float*)d_in[wa_i[l] + 3];
        s.out = ws + (right ? tr_off[l] : tl_off[l]);
        s.CIN = C[l]; s.H = H[l]; s.W = W[l];
        s.right = right ? 1 : 0;
        int OH = H[l] / 4, W4 = W[l] / 4;
        s.nit = right ? OH * W[l] : OH * W4;   // 1 output px per thread
        s.npix = s.nit;
        s.blk0 = blk;
        blk += (s.nit + 255) / 256;
    }
    conv_uber<<<blk, 256, 0, stream>>>(ct);

    // ---- cv table: level 1 (biggest) first; 16 px x 16 d-chunks per block ----
    const float* feat[5] = {ws + tl_off[0], ws + tl_off[1], fl[0], fl[1], fl[2]};
    const int   CF[5]    = {16, 16, 32, 24, 24};
    CvTab vt;
    blk = 0;
    for (int i = 0; i < 5; i++) {
        int l = 4 - i;
        CvSeg& s = vt.seg[i];
        s.tl = ws + tl_off[l]; s.tr = ws + tr_off[l];
        s.feat = feat[l];
        s.dw = (const float*)d_in[dw_i[l]];
        s.db = (const float*)d_in[dw_i[l] + 1];
        s.cv = out + cv_off[l]; s.hyp = out + hyp_off[l];
        s.h = H[l] / 4; s.w4 = W[l] / 4; s.w = W[l]; s.D = D[l];
        int ngroups = D[l] / 4;
        s.gpc = (ngroups + 15) / 16;
        s.CF = CF[l];
        s.blk0 = blk;
        blk += (s.h * s.w4 + 15) / 16;
    }
    cv_hyp_uber<<<blk, 256, 0, stream>>>(vt);
}